// Round 1
// baseline (1320.055 us; speedup 1.0000x reference)
//
#include <hip/hip_runtime.h>
#include <math.h>

#define B 16
#define C 128
#define H 32
#define W 512

// ---------------- Kernel A: grouped (1x3) conv, groups=2 ----------------
// grid (16, 128, 16), block 256. Each thread computes 4 consecutive w.
__global__ __launch_bounds__(256) void conv_grouped(const float* __restrict__ x,
                                                    const float* __restrict__ wg,
                                                    float* __restrict__ y) {
    const int p  = blockIdx.x * 256 + threadIdx.x;   // 0..4095 over (h, w/4)
    const int h  = p >> 7;
    const int j  = p & 127;
    const int w0 = j << 2;
    const int o  = blockIdx.y;
    const int b  = blockIdx.z;
    const int g  = o >> 6;
    const float* wp = wg + o * 192;                  // wg[o, ci, 0, kw]
    const float* xb = x + ((size_t)(b * C + g * 64) * H + h) * W;
    const bool hl = (j > 0), hr = (j < 127);
    float a0 = 0.f, a1 = 0.f, a2 = 0.f, a3 = 0.f;
#pragma unroll 4
    for (int ci = 0; ci < 64; ++ci) {
        const float* row = xb + ci * (H * W);
        const float4 xv = *(const float4*)(row + w0);
        const float  xl = hl ? row[w0 - 1] : 0.f;
        const float  xr = hr ? row[w0 + 4] : 0.f;
        const float k0 = wp[ci * 3 + 0];
        const float k1 = wp[ci * 3 + 1];
        const float k2 = wp[ci * 3 + 2];
        a0 += xl   * k0 + xv.x * k1 + xv.y * k2;
        a1 += xv.x * k0 + xv.y * k1 + xv.z * k2;
        a2 += xv.y * k0 + xv.z * k1 + xv.w * k2;
        a3 += xv.z * k0 + xv.w * k1 + xr   * k2;
    }
    *(float4*)(y + ((size_t)(b * C + o) * H + h) * W + w0) = make_float4(a0, a1, a2, a3);
}

// ---------------- Kernel B1: pool over C -> [B,2,H,W] ----------------
__global__ __launch_bounds__(256) void pool_c(const float* __restrict__ y,
                                              float* __restrict__ pool1) {
    const int w = blockIdx.x * 256 + threadIdx.x;
    const int h = blockIdx.y;
    const int b = blockIdx.z;
    float m = -INFINITY, s = 0.f;
    for (int c = 0; c < C; ++c) {
        const float v = y[((size_t)(b * C + c) * H + h) * W + w];
        m = fmaxf(m, v);
        s += v;
    }
    pool1[((size_t)(b * 2 + 0) * H + h) * W + w] = m;
    pool1[((size_t)(b * 2 + 1) * H + h) * W + w] = s * (1.f / C);
}

// ---------------- Kernel B2: pool over H -> [B,2,C,W] ----------------
__global__ __launch_bounds__(256) void pool_h(const float* __restrict__ y,
                                              float* __restrict__ pool2) {
    const int w = blockIdx.x * 256 + threadIdx.x;
    const int c = blockIdx.y;
    const int b = blockIdx.z;
    float m = -INFINITY, s = 0.f;
    for (int h = 0; h < H; ++h) {
        const float v = y[((size_t)(b * C + c) * H + h) * W + w];
        m = fmaxf(m, v);
        s += v;
    }
    pool2[((size_t)(b * 2 + 0) * C + c) * W + w] = m;
    pool2[((size_t)(b * 2 + 1) * C + c) * W + w] = s * (1.f / H);
}

// ---------------- Kernel B3: pool over W -> [B,2,H,C] ----------------
// one wave per row of 512; 4 waves (256 threads) per block
__global__ __launch_bounds__(256) void pool_w(const float* __restrict__ y,
                                              float* __restrict__ pool3) {
    const int wave = threadIdx.x >> 6;
    const int lane = threadIdx.x & 63;
    const int row  = blockIdx.x * 4 + wave;          // row = (b*C+c)*H + h
    const float* r = y + (size_t)row * W;
    float m = -INFINITY, s = 0.f;
#pragma unroll
    for (int k = 0; k < 8; ++k) {
        const float v = r[lane + k * 64];
        m = fmaxf(m, v);
        s += v;
    }
    for (int off = 32; off; off >>= 1) {
        m = fmaxf(m, __shfl_xor(m, off));
        s += __shfl_xor(s, off);
    }
    if (lane == 0) {
        const int b = row >> 12, c = (row >> 5) & 127, h = row & 31;
        pool3[((size_t)(b * 2 + 0) * H + h) * C + c] = m;
        pool3[((size_t)(b * 2 + 1) * H + h) * C + c] = s * (1.f / W);
    }
}

// ---------------- Kernel C: 7x7 conv (2->1 ch) + sigmoid ----------------
__global__ __launch_bounds__(256) void conv7_sig(const float* __restrict__ pin,
                                                 const float* __restrict__ wt,
                                                 float* __restrict__ sout,
                                                 int P, int Q, int total) {
    const int n = blockIdx.x * 256 + threadIdx.x;
    if (n >= total) return;
    const int q = n % Q;
    const int t = n / Q;
    const int p = t % P;
    const int b = t / P;
    float acc = 0.f;
#pragma unroll
    for (int c2 = 0; c2 < 2; ++c2) {
#pragma unroll
        for (int i = 0; i < 7; ++i) {
            const int pp = p + i - 3;
            if (pp < 0 || pp >= P) continue;
#pragma unroll
            for (int jj = 0; jj < 7; ++jj) {
                const int qq = q + jj - 3;
                if (qq < 0 || qq >= Q) continue;
                acc += pin[((size_t)(b * 2 + c2) * P + pp) * Q + qq] * wt[c2 * 49 + i * 7 + jj];
            }
        }
    }
    sout[n] = 1.f / (1.f + expf(-acc));
}

// ---------------- Kernel D: out = y * (s1+s2+s3)/3, in place ----------------
__global__ __launch_bounds__(256) void final_mul(float* __restrict__ y,
                                                 const float* __restrict__ s1,
                                                 const float* __restrict__ s2,
                                                 const float* __restrict__ s3) {
    const int n   = blockIdx.x * 256 + threadIdx.x;  // per float4
    const int j   = n & 127;
    const int row = n >> 7;                          // (b*C+c)*H + h
    const int h = row & 31, c = (row >> 5) & 127, b = row >> 12;
    const int w0 = j << 2;
    float4 yv = *(float4*)(y + (size_t)row * W + w0);
    const float4 v1 = *(const float4*)(s1 + ((size_t)b * H + h) * W + w0);
    const float4 v2 = *(const float4*)(s2 + ((size_t)b * C + c) * W + w0);
    const float  g3 = s3[((size_t)b * H + h) * C + c];
    const float k = 1.f / 3.f;
    float4 o;
    o.x = yv.x * (v1.x + v2.x + g3) * k;
    o.y = yv.y * (v1.y + v2.y + g3) * k;
    o.z = yv.z * (v1.z + v2.z + g3) * k;
    o.w = yv.w * (v1.w + v2.w + g3) * k;
    *(float4*)(y + (size_t)row * W + w0) = o;
}

extern "C" void kernel_launch(void* const* d_in, const int* in_sizes, int n_in,
                              void* d_out, int out_size, void* d_ws, size_t ws_size,
                              hipStream_t stream) {
    const float* x  = (const float*)d_in[0];
    const float* wg = (const float*)d_in[1];
    const float* w1 = (const float*)d_in[2];
    const float* w2 = (const float*)d_in[3];
    const float* w3 = (const float*)d_in[4];
    float* y  = (float*)d_out;       // y lives in d_out; final multiply is in-place
    float* ws = (float*)d_ws;

    float* pool1 = ws;               // [B,2,H,W]  524288
    float* pool2 = ws + 524288;      // [B,2,C,W]  2097152
    float* pool3 = ws + 2621440;     // [B,2,H,C]  131072
    float* s1    = ws + 2752512;     // [B,H,W]    262144
    float* s2    = ws + 3014656;     // [B,C,W]    1048576
    float* s3    = ws + 4063232;     // [B,H,C]    65536

    conv_grouped<<<dim3(16, 128, 16), 256, 0, stream>>>(x, wg, y);

    pool_c<<<dim3(2, H, B), 256, 0, stream>>>(y, pool1);
    pool_h<<<dim3(2, C, B), 256, 0, stream>>>(y, pool2);
    pool_w<<<dim3((B * C * H) / 4), 256, 0, stream>>>(y, pool3);

    conv7_sig<<<dim3(262144 / 256), 256, 0, stream>>>(pool1, w1, s1, H, W, 262144);
    conv7_sig<<<dim3(1048576 / 256), 256, 0, stream>>>(pool2, w2, s2, C, W, 1048576);
    conv7_sig<<<dim3(65536 / 256), 256, 0, stream>>>(pool3, w3, s3, H, C, 65536);

    final_mul<<<dim3((B * C * H * W / 4) / 256), 256, 0, stream>>>(y, s1, s2, s3);
}

// Round 2
// 391.347 us; speedup vs baseline: 3.3731x; 3.3731x over previous
//
#include <hip/hip_runtime.h>
#include <math.h>

#define B 16
#define C 128
#define H 32
#define W 512

// ---------------- Kernel A: grouped (1x3) conv, groups=2, LDS-staged ----------------
// One block per (group, h, b): computes all 64 output channels of the group for one
// (b,h) row. x rows staged in LDS (2 chunks of 32 ci), read from HBM exactly once.
// Thread tile: 8 o x 4 w. Fused pool-over-W epilogue writes pool3.
__global__ __launch_bounds__(1024, 4) void conv_grouped_lds(
    const float* __restrict__ x, const float* __restrict__ wg,
    float* __restrict__ y, float* __restrict__ pool3) {
    // row layout: [4 zeros][512 data][4 zeros] -> all f4 reads/writes 16B aligned
    __shared__ float xs[32][520];
    __shared__ float part[16][8][2];

    const int g = blockIdx.x;
    const int h = blockIdx.y;
    const int b = blockIdx.z;
    const int t = threadIdx.x;
    const int lane = t & 63;
    const int wave = t >> 6;                                  // 0..15
    const int half = wave & 1;                                // w half (0/1)
    const int o_base = __builtin_amdgcn_readfirstlane(wave >> 1) * 8;  // SGPR
    const int w0 = (half << 8) + lane * 4;                    // output w start

    if (t < 32) {                                             // zero halos (persist)
        *(float4*)&xs[t][0]   = make_float4(0.f, 0.f, 0.f, 0.f);
        *(float4*)&xs[t][516] = make_float4(0.f, 0.f, 0.f, 0.f);
    }

    float acc[8][4];
#pragma unroll
    for (int i = 0; i < 8; ++i)
#pragma unroll
        for (int j = 0; j < 4; ++j) acc[i][j] = 0.f;

    const int r  = t >> 5;                                    // staging row 0..31
    const int cl = t & 31;                                    // staging col lane

    for (int chunk = 0; chunk < 2; ++chunk) {
        __syncthreads();
        {
            const float* xrow = x + ((size_t)(b * C + g * 64 + chunk * 32 + r) * H + h) * W;
            const float4 v0 = *(const float4*)(xrow + cl * 4);
            const float4 v1 = *(const float4*)(xrow + cl * 4 + 128);
            const float4 v2 = *(const float4*)(xrow + cl * 4 + 256);
            const float4 v3 = *(const float4*)(xrow + cl * 4 + 384);
            *(float4*)&xs[r][4 + cl * 4]       = v0;
            *(float4*)&xs[r][4 + cl * 4 + 128] = v1;
            *(float4*)&xs[r][4 + cl * 4 + 256] = v2;
            *(float4*)&xs[r][4 + cl * 4 + 384] = v3;
        }
        __syncthreads();
        // weights: wave-uniform (SGPR) base -> scalar loads
        const float* wp = wg + ((size_t)(g * 64 + o_base) * 64 + chunk * 32) * 3;
#pragma unroll 2
        for (int ci = 0; ci < 32; ++ci) {
            // D = x[w0-4..w0-1], E = x[w0..w0+3], F = x[w0+4..w0+7]
            const float4 D = *(const float4*)&xs[ci][w0];
            const float4 E = *(const float4*)&xs[ci][w0 + 4];
            const float4 F = *(const float4*)&xs[ci][w0 + 8];
#pragma unroll
            for (int i = 0; i < 8; ++i) {
                const float k0 = wp[i * 192 + ci * 3 + 0];
                const float k1 = wp[i * 192 + ci * 3 + 1];
                const float k2 = wp[i * 192 + ci * 3 + 2];
                acc[i][0] += D.w * k0 + E.x * k1 + E.y * k2;
                acc[i][1] += E.x * k0 + E.y * k1 + E.z * k2;
                acc[i][2] += E.y * k0 + E.z * k1 + E.w * k2;
                acc[i][3] += E.z * k0 + E.w * k1 + F.x * k2;
            }
        }
    }

    // store y
#pragma unroll
    for (int i = 0; i < 8; ++i) {
        *(float4*)(y + ((size_t)(b * C + g * 64 + o_base + i) * H + h) * W + w0) =
            make_float4(acc[i][0], acc[i][1], acc[i][2], acc[i][3]);
    }

    // fused pool over W -> pool3 [B,2,H,C]
    float m[8], s[8];
#pragma unroll
    for (int i = 0; i < 8; ++i) {
        m[i] = fmaxf(fmaxf(acc[i][0], acc[i][1]), fmaxf(acc[i][2], acc[i][3]));
        s[i] = acc[i][0] + acc[i][1] + acc[i][2] + acc[i][3];
    }
#pragma unroll
    for (int off = 32; off; off >>= 1) {
#pragma unroll
        for (int i = 0; i < 8; ++i) {
            m[i] = fmaxf(m[i], __shfl_xor(m[i], off));
            s[i] += __shfl_xor(s[i], off);
        }
    }
    if (lane == 0) {
#pragma unroll
        for (int i = 0; i < 8; ++i) {
            part[wave][i][0] = m[i];
            part[wave][i][1] = s[i];
        }
    }
    __syncthreads();
    if (t < 64) {
        const int k = t >> 3, i = t & 7;                      // o = k*8+i = t
        const float mm = fmaxf(part[2 * k][i][0], part[2 * k + 1][i][0]);
        const float ss = (part[2 * k][i][1] + part[2 * k + 1][i][1]) * (1.f / W);
        pool3[((size_t)(b * 2 + 0) * H + h) * C + g * 64 + t] = mm;
        pool3[((size_t)(b * 2 + 1) * H + h) * C + g * 64 + t] = ss;
    }
}

// ---------------- Kernel B1: pool over C -> [B,2,H,W] ----------------
__global__ __launch_bounds__(256) void pool_c(const float* __restrict__ y,
                                              float* __restrict__ pool1) {
    const int w = blockIdx.x * 256 + threadIdx.x;
    const int h = blockIdx.y;
    const int b = blockIdx.z;
    float m = -INFINITY, s = 0.f;
    for (int c = 0; c < C; ++c) {
        const float v = y[((size_t)(b * C + c) * H + h) * W + w];
        m = fmaxf(m, v);
        s += v;
    }
    pool1[((size_t)(b * 2 + 0) * H + h) * W + w] = m;
    pool1[((size_t)(b * 2 + 1) * H + h) * W + w] = s * (1.f / C);
}

// ---------------- Kernel B2: pool over H -> [B,2,C,W] ----------------
__global__ __launch_bounds__(256) void pool_h(const float* __restrict__ y,
                                              float* __restrict__ pool2) {
    const int w = blockIdx.x * 256 + threadIdx.x;
    const int c = blockIdx.y;
    const int b = blockIdx.z;
    float m = -INFINITY, s = 0.f;
    for (int h = 0; h < H; ++h) {
        const float v = y[((size_t)(b * C + c) * H + h) * W + w];
        m = fmaxf(m, v);
        s += v;
    }
    pool2[((size_t)(b * 2 + 0) * C + c) * W + w] = m;
    pool2[((size_t)(b * 2 + 1) * C + c) * W + w] = s * (1.f / H);
}

// ---------------- Kernel C: 7x7 conv (2->1 ch) + sigmoid ----------------
__global__ __launch_bounds__(256) void conv7_sig(const float* __restrict__ pin,
                                                 const float* __restrict__ wt,
                                                 float* __restrict__ sout,
                                                 int P, int Q, int total) {
    const int n = blockIdx.x * 256 + threadIdx.x;
    if (n >= total) return;
    const int q = n % Q;
    const int t = n / Q;
    const int p = t % P;
    const int b = t / P;
    float acc = 0.f;
#pragma unroll
    for (int c2 = 0; c2 < 2; ++c2) {
#pragma unroll
        for (int i = 0; i < 7; ++i) {
            const int pp = p + i - 3;
            if (pp < 0 || pp >= P) continue;
#pragma unroll
            for (int jj = 0; jj < 7; ++jj) {
                const int qq = q + jj - 3;
                if (qq < 0 || qq >= Q) continue;
                acc += pin[((size_t)(b * 2 + c2) * P + pp) * Q + qq] * wt[c2 * 49 + i * 7 + jj];
            }
        }
    }
    sout[n] = 1.f / (1.f + expf(-acc));
}

// ---------------- Kernel D: out = y * (s1+s2+s3)/3, in place ----------------
__global__ __launch_bounds__(256) void final_mul(float* __restrict__ y,
                                                 const float* __restrict__ s1,
                                                 const float* __restrict__ s2,
                                                 const float* __restrict__ s3) {
    const int n   = blockIdx.x * 256 + threadIdx.x;  // per float4
    const int j   = n & 127;
    const int row = n >> 7;                          // (b*C+c)*H + h
    const int h = row & 31, c = (row >> 5) & 127, b = row >> 12;
    const int w0 = j << 2;
    float4 yv = *(float4*)(y + (size_t)row * W + w0);
    const float4 v1 = *(const float4*)(s1 + ((size_t)b * H + h) * W + w0);
    const float4 v2 = *(const float4*)(s2 + ((size_t)b * C + c) * W + w0);
    const float  g3 = s3[((size_t)b * H + h) * C + c];
    const float k = 1.f / 3.f;
    float4 o;
    o.x = yv.x * (v1.x + v2.x + g3) * k;
    o.y = yv.y * (v1.y + v2.y + g3) * k;
    o.z = yv.z * (v1.z + v2.z + g3) * k;
    o.w = yv.w * (v1.w + v2.w + g3) * k;
    *(float4*)(y + (size_t)row * W + w0) = o;
}

extern "C" void kernel_launch(void* const* d_in, const int* in_sizes, int n_in,
                              void* d_out, int out_size, void* d_ws, size_t ws_size,
                              hipStream_t stream) {
    const float* x  = (const float*)d_in[0];
    const float* wg = (const float*)d_in[1];
    const float* w1 = (const float*)d_in[2];
    const float* w2 = (const float*)d_in[3];
    const float* w3 = (const float*)d_in[4];
    float* y  = (float*)d_out;       // y lives in d_out; final multiply is in-place
    float* ws = (float*)d_ws;

    float* pool1 = ws;               // [B,2,H,W]  524288
    float* pool2 = ws + 524288;      // [B,2,C,W]  2097152
    float* pool3 = ws + 2621440;     // [B,2,H,C]  131072
    float* s1    = ws + 2752512;     // [B,H,W]    262144
    float* s2    = ws + 3014656;     // [B,C,W]    1048576
    float* s3    = ws + 4063232;     // [B,H,C]    65536

    conv_grouped_lds<<<dim3(2, H, B), 1024, 0, stream>>>(x, wg, y, pool3);

    pool_c<<<dim3(2, H, B), 256, 0, stream>>>(y, pool1);
    pool_h<<<dim3(2, C, B), 256, 0, stream>>>(y, pool2);

    conv7_sig<<<dim3(262144 / 256), 256, 0, stream>>>(pool1, w1, s1, H, W, 262144);
    conv7_sig<<<dim3(1048576 / 256), 256, 0, stream>>>(pool2, w2, s2, C, W, 1048576);
    conv7_sig<<<dim3(65536 / 256), 256, 0, stream>>>(pool3, w3, s3, H, C, 65536);

    final_mul<<<dim3((B * C * H * W / 4) / 256), 256, 0, stream>>>(y, s1, s2, s3);
}

// Round 3
// 373.612 us; speedup vs baseline: 3.5332x; 1.0475x over previous
//
#include <hip/hip_runtime.h>
#include <math.h>

#define B 16
#define C 128
#define H 32
#define W 512

// ---------------- Kernel A: grouped (1x3) conv, groups=2, LDS-staged ----------------
// One block per (group, h, b). 512 threads = 8 waves; wave = otile*2 + half;
// thread tile 16 o x 4 w. x staged in LDS once (2 chunks of 32 ci).
// Fused: pool over W (-> pool3) and per-group partial pool over C (-> pool1p).
__global__ __launch_bounds__(512, 4) void conv_grouped_lds(
    const float* __restrict__ x, const float* __restrict__ wg,
    float* __restrict__ y, float* __restrict__ pool3, float* __restrict__ pool1p) {
    // xs row layout: [4 zeros][512 data][4 zeros]
    __shared__ __align__(16) char smem[32 * 520 * 4];
    float (*xs)[520] = (float(*)[520])smem;

    const int g = blockIdx.x;
    const int h = blockIdx.y;
    const int b = blockIdx.z;
    const int t = threadIdx.x;
    const int lane = t & 63;
    const int wave = t >> 6;                                   // 0..7
    const int half = wave & 1;                                 // w half
    const int o_base = __builtin_amdgcn_readfirstlane(wave >> 1) * 16;  // SGPR
    const int w0 = (half << 8) + lane * 4;

    if (t < 32) {                                              // zero halos (persist)
        *(float4*)&xs[t][0]   = make_float4(0.f, 0.f, 0.f, 0.f);
        *(float4*)&xs[t][516] = make_float4(0.f, 0.f, 0.f, 0.f);
    }

    float acc[16][4];
#pragma unroll
    for (int i = 0; i < 16; ++i)
#pragma unroll
        for (int j = 0; j < 4; ++j) acc[i][j] = 0.f;

    const int r  = t >> 4;                                     // staging row 0..31
    const int c4 = (t & 15) * 4;                               // staging col

    for (int chunk = 0; chunk < 2; ++chunk) {
        __syncthreads();
        {
            const float* xrow = x + ((size_t)(b * C + g * 64 + chunk * 32 + r) * H + h) * W;
#pragma unroll
            for (int j = 0; j < 8; ++j)
                *(float4*)&xs[r][4 + c4 + j * 64] = *(const float4*)(xrow + c4 + j * 64);
        }
        __syncthreads();
        const float* wp = wg + (size_t)(g * 64 + o_base) * 192 + chunk * 96;
#pragma unroll 2
        for (int ci = 0; ci < 32; ++ci) {
            const float4 D = *(const float4*)&xs[ci][w0];      // x[w0-4..w0-1]
            const float4 E = *(const float4*)&xs[ci][w0 + 4];  // x[w0..w0+3]
            const float4 F = *(const float4*)&xs[ci][w0 + 8];  // x[w0+4..w0+7]
#pragma unroll
            for (int i = 0; i < 16; ++i) {
                const float k0 = wp[i * 192 + ci * 3 + 0];
                const float k1 = wp[i * 192 + ci * 3 + 1];
                const float k2 = wp[i * 192 + ci * 3 + 2];
                acc[i][0] += D.w * k0 + E.x * k1 + E.y * k2;
                acc[i][1] += E.x * k0 + E.y * k1 + E.z * k2;
                acc[i][2] += E.y * k0 + E.z * k1 + E.w * k2;
                acc[i][3] += E.z * k0 + E.w * k1 + F.x * k2;
            }
        }
    }

    // store y
#pragma unroll
    for (int i = 0; i < 16; ++i)
        *(float4*)(y + ((size_t)(b * C + g * 64 + o_base + i) * H + h) * W + w0) =
            make_float4(acc[i][0], acc[i][1], acc[i][2], acc[i][3]);

    __syncthreads();                       // xs no longer needed; reuse for reductions
    float* pc = (float*)smem;              // [8][64][4][2] = 16 KB
    float* pw = (float*)(smem + 16384);    // [8][16][2]    = 1 KB

    // ---- pool over W (per-channel m/s across this row) ----
    {
        float wm[16], wsv[16];
#pragma unroll
        for (int i = 0; i < 16; ++i) {
            wm[i]  = fmaxf(fmaxf(acc[i][0], acc[i][1]), fmaxf(acc[i][2], acc[i][3]));
            wsv[i] = acc[i][0] + acc[i][1] + acc[i][2] + acc[i][3];
        }
#pragma unroll
        for (int off = 32; off; off >>= 1)
#pragma unroll
            for (int i = 0; i < 16; ++i) {
                wm[i]  = fmaxf(wm[i], __shfl_xor(wm[i], off));
                wsv[i] += __shfl_xor(wsv[i], off);
            }
        if (lane == 0)
#pragma unroll
            for (int i = 0; i < 16; ++i) {
                pw[wave * 32 + i * 2 + 0] = wm[i];
                pw[wave * 32 + i * 2 + 1] = wsv[i];
            }
    }
    // ---- partial pool over C (this block's 64 channels) ----
    {
        float cm[4], csv[4];
#pragma unroll
        for (int j = 0; j < 4; ++j) { cm[j] = acc[0][j]; csv[j] = acc[0][j]; }
#pragma unroll
        for (int i = 1; i < 16; ++i)
#pragma unroll
            for (int j = 0; j < 4; ++j) {
                cm[j]  = fmaxf(cm[j], acc[i][j]);
                csv[j] += acc[i][j];
            }
#pragma unroll
        for (int j = 0; j < 4; ++j) {
            pc[(wave * 64 + lane) * 8 + j * 2 + 0] = cm[j];
            pc[(wave * 64 + lane) * 8 + j * 2 + 1] = csv[j];
        }
    }
    __syncthreads();

    if (t < 64) {                          // pool_w combine: c = g*64 + t
        const int ot = t >> 4, i = t & 15;
        const float m0 = fmaxf(pw[(2 * ot) * 32 + i * 2], pw[(2 * ot + 1) * 32 + i * 2]);
        const float s0 = (pw[(2 * ot) * 32 + i * 2 + 1] + pw[(2 * ot + 1) * 32 + i * 2 + 1]) * (1.f / W);
        const int c = g * 64 + ot * 16 + i;
        pool3[((size_t)(b * 2 + 0) * H + h) * C + c] = m0;
        pool3[((size_t)(b * 2 + 1) * H + h) * C + c] = s0;
    }
    {                                      // pool_c partial combine over 4 otiles
        const int hf = t >> 8, l2 = (t >> 2) & 63, j = t & 3;
        const int w = (hf << 8) + l2 * 4 + j;
        float m0 = -INFINITY, s0 = 0.f;
#pragma unroll
        for (int ot = 0; ot < 4; ++ot) {
            const int idx = ((ot * 2 + hf) * 64 + l2) * 8 + j * 2;
            m0 = fmaxf(m0, pc[idx]);
            s0 += pc[idx + 1];
        }
        pool1p[((size_t)(g * B + b) * 2 + 0) * (H * W) + h * W + w] = m0;
        pool1p[((size_t)(g * B + b) * 2 + 1) * (H * W) + h * W + w] = s0;
    }
}

// ---------------- combine pool1 partials (2 groups) -> pool1 [B,2,H,W] ----------------
__global__ __launch_bounds__(256) void combine_pool1(const float* __restrict__ p1p,
                                                     float* __restrict__ pool1) {
    const int n = blockIdx.x * 256 + threadIdx.x;   // over B*H*W/4
    const int b = n >> 12;
    const int o = (n & 4095) * 4;                   // h*W+w offset
    const float4 m0 = *(const float4*)(p1p + ((size_t)(0 * B + b) * 2 + 0) * (H * W) + o);
    const float4 m1 = *(const float4*)(p1p + ((size_t)(1 * B + b) * 2 + 0) * (H * W) + o);
    const float4 s0 = *(const float4*)(p1p + ((size_t)(0 * B + b) * 2 + 1) * (H * W) + o);
    const float4 s1 = *(const float4*)(p1p + ((size_t)(1 * B + b) * 2 + 1) * (H * W) + o);
    float4 mo, so;
    mo.x = fmaxf(m0.x, m1.x); mo.y = fmaxf(m0.y, m1.y);
    mo.z = fmaxf(m0.z, m1.z); mo.w = fmaxf(m0.w, m1.w);
    const float k = 1.f / C;
    so.x = (s0.x + s1.x) * k; so.y = (s0.y + s1.y) * k;
    so.z = (s0.z + s1.z) * k; so.w = (s0.w + s1.w) * k;
    *(float4*)(pool1 + ((size_t)(b * 2 + 0) * H * W) + o) = mo;
    *(float4*)(pool1 + ((size_t)(b * 2 + 1) * H * W) + o) = so;
}

// ---------------- pool over H -> [B,2,C,W] ----------------
__global__ __launch_bounds__(256) void pool_h(const float* __restrict__ y,
                                              float* __restrict__ pool2) {
    const int w = blockIdx.x * 256 + threadIdx.x;
    const int c = blockIdx.y;
    const int b = blockIdx.z;
    float m = -INFINITY, s = 0.f;
    for (int h = 0; h < H; ++h) {
        const float v = y[((size_t)(b * C + c) * H + h) * W + w];
        m = fmaxf(m, v);
        s += v;
    }
    pool2[((size_t)(b * 2 + 0) * C + c) * W + w] = m;
    pool2[((size_t)(b * 2 + 1) * C + c) * W + w] = s * (1.f / H);
}

// ---------------- 7x7 conv (2->1 ch) + sigmoid ----------------
__global__ __launch_bounds__(256) void conv7_sig(const float* __restrict__ pin,
                                                 const float* __restrict__ wt,
                                                 float* __restrict__ sout,
                                                 int P, int Q, int total) {
    const int n = blockIdx.x * 256 + threadIdx.x;
    if (n >= total) return;
    const int q = n % Q;
    const int t = n / Q;
    const int p = t % P;
    const int b = t / P;
    float acc = 0.f;
#pragma unroll
    for (int c2 = 0; c2 < 2; ++c2) {
#pragma unroll
        for (int i = 0; i < 7; ++i) {
            const int pp = p + i - 3;
            if (pp < 0 || pp >= P) continue;
#pragma unroll
            for (int jj = 0; jj < 7; ++jj) {
                const int qq = q + jj - 3;
                if (qq < 0 || qq >= Q) continue;
                acc += pin[((size_t)(b * 2 + c2) * P + pp) * Q + qq] * wt[c2 * 49 + i * 7 + jj];
            }
        }
    }
    sout[n] = 1.f / (1.f + expf(-acc));
}

// ---------------- out = y * (s1+s2+s3)/3, in place ----------------
__global__ __launch_bounds__(256) void final_mul(float* __restrict__ y,
                                                 const float* __restrict__ s1,
                                                 const float* __restrict__ s2,
                                                 const float* __restrict__ s3) {
    const int n   = blockIdx.x * 256 + threadIdx.x;  // per float4
    const int j   = n & 127;
    const int row = n >> 7;                          // (b*C+c)*H + h
    const int h = row & 31, c = (row >> 5) & 127, b = row >> 12;
    const int w0 = j << 2;
    float4 yv = *(float4*)(y + (size_t)row * W + w0);
    const float4 v1 = *(const float4*)(s1 + ((size_t)b * H + h) * W + w0);
    const float4 v2 = *(const float4*)(s2 + ((size_t)b * C + c) * W + w0);
    const float  g3 = s3[((size_t)b * H + h) * C + c];
    const float k = 1.f / 3.f;
    float4 o;
    o.x = yv.x * (v1.x + v2.x + g3) * k;
    o.y = yv.y * (v1.y + v2.y + g3) * k;
    o.z = yv.z * (v1.z + v2.z + g3) * k;
    o.w = yv.w * (v1.w + v2.w + g3) * k;
    *(float4*)(y + (size_t)row * W + w0) = o;
}

extern "C" void kernel_launch(void* const* d_in, const int* in_sizes, int n_in,
                              void* d_out, int out_size, void* d_ws, size_t ws_size,
                              hipStream_t stream) {
    const float* x  = (const float*)d_in[0];
    const float* wg = (const float*)d_in[1];
    const float* w1 = (const float*)d_in[2];
    const float* w2 = (const float*)d_in[3];
    const float* w3 = (const float*)d_in[4];
    float* y  = (float*)d_out;       // y lives in d_out; final multiply is in-place
    float* ws = (float*)d_ws;

    // pool1p [2,B,2,H,W] (1M floats) aliases pool2's region; it is dead before
    // pool_h writes pool2 (stream-ordered).
    float* pool1p = ws;              // [2,B,2,H,W] 1048576
    float* pool2  = ws;              // [B,2,C,W]   2097152
    float* pool1  = ws + 2097152;    // [B,2,H,W]   524288
    float* pool3  = ws + 2621440;    // [B,2,H,C]   131072
    float* s1     = ws + 2752512;    // [B,H,W]     262144
    float* s2     = ws + 3014656;    // [B,C,W]     1048576
    float* s3     = ws + 4063232;    // [B,H,C]     65536

    conv_grouped_lds<<<dim3(2, H, B), 512, 0, stream>>>(x, wg, y, pool3, pool1p);

    combine_pool1<<<dim3((B * H * W / 4) / 256), 256, 0, stream>>>(pool1p, pool1);
    pool_h<<<dim3(2, C, B), 256, 0, stream>>>(y, pool2);

    conv7_sig<<<dim3(262144 / 256), 256, 0, stream>>>(pool1, w1, s1, H, W, 262144);
    conv7_sig<<<dim3(1048576 / 256), 256, 0, stream>>>(pool2, w2, s2, C, W, 1048576);
    conv7_sig<<<dim3(65536 / 256), 256, 0, stream>>>(pool3, w3, s3, H, C, 65536);

    final_mul<<<dim3((B * C * H * W / 4) / 256), 256, 0, stream>>>(y, s1, s2, s3);
}